// Round 26
// baseline (69.229 us; speedup 1.0000x reference)
//
#include <hip/hip_runtime.h>
#include <hip/hip_bf16.h>

#define FEATN 501
#define KPAD 1024
#define MSTRIDE 1032   // Ml row stride (ushorts); 2064B, 16B-aligned
#define NB 8192
#define NT 512
#define DTC 0.01f

typedef __attribute__((ext_vector_type(8))) short short8;
typedef __attribute__((ext_vector_type(4))) float f32x4;

__device__ __forceinline__ float softplus_f(float x) {
    return fmaxf(x, 0.f) + log1pf(expf(-fabsf(x)));
}
__device__ __forceinline__ ushort f2bf(float x) {
    __hip_bfloat16 h = __float2bfloat16(x);   // RNE
    return *reinterpret_cast<ushort*>(&h);
}
__device__ __forceinline__ void gl_lds16(const void* g, void* l) {
    __builtin_amdgcn_global_load_lds(
        (const __attribute__((address_space(1))) void*)g,
        (__attribute__((address_space(3))) void*)l, 16, 0, 0);
}
__device__ __forceinline__ float dpp_add(float x, const int ctrl) {
    int s = __builtin_bit_cast(int, x);
    int y;
    switch (ctrl) {
    case 0xB1:  y = __builtin_amdgcn_update_dpp(0, s, 0xB1, 0xf, 0xf, true); break;
    case 0x4E:  y = __builtin_amdgcn_update_dpp(0, s, 0x4E, 0xf, 0xf, true); break;
    default:    y = __builtin_amdgcn_update_dpp(0, s, 0x141, 0xf, 0xf, true); break;
    }
    return x + __builtin_bit_cast(float, y);
}

// Wt2 tiled layout: idx(k,h) = ((s*128 + h)*4 + kg)*8 + kk  (unchanged)
__global__ __launch_bounds__(256) void wtrans_kernel(
    const float* __restrict__ Bw1, const float* __restrict__ bw1,
    ushort* __restrict__ Wt) {
    const int h = blockIdx.x;
    const float* W = (h < 64) ? Bw1 : bw1;
    const int col = h & 63;
    #pragma unroll
    for (int it = 0; it < 4; ++it) {
        const int k = it * 256 + threadIdx.x;
        const int ksrc = (k < FEATN) ? k
                       : (k >= 512 && k < 512 + FEATN) ? k - 11 : -1;
        const float v = (ksrc >= 0) ? W[(size_t)ksrc * 64 + col] : 0.f;
        Wt[(size_t)(((k >> 5) * 128 + h) * 4 + ((k >> 3) & 3)) * 8 + (k & 7)] =
            f2bf(v);
    }
}

// ---------------- prep: streaming A-phase (grid 2048, full TLP) ------------
__global__ __launch_bounds__(256) void prep_kernel(
    const float* __restrict__ E, const float* __restrict__ nu,
    float* __restrict__ xi, float* __restrict__ cw) {
    const int b = blockIdx.x * 4 + (threadIdx.x >> 6);
    const int lane = threadIdx.x & 63;
    const size_t base = (size_t)b * FEATN;
    ushort* mb = (ushort*)(xi + (size_t)b * 4096 + 512);
    float s1 = 0.f, s2 = 0.f;
    for (int i = lane; i < FEATN; i += 64) {
        const float Ev = E[base + i];
        const float nv = nu[base + i];
        const float inv = 1.0f / nv;
        s1 += inv;
        s2 = fmaf(Ev, inv * inv, s2);
        mb[i] = f2bf(Ev);
        mb[512 + i] = f2bf(nv);
    }
    if (lane < 11) {                      // zero pads 501..511, 1013..1023
        mb[FEATN + lane] = 0;
        mb[512 + FEATN + lane] = 0;
    }
    #pragma unroll
    for (int o = 32; o; o >>= 1) {
        s1 += __shfl_xor(s1, o);
        s2 += __shfl_xor(s2, o);
    }
    if (lane == 0) {
        const float np = (float)FEATN / s1;
        float* cb = cw + (size_t)b * 32;
        cb[26] = np;
        cb[27] = (s2 / (float)FEATN) * np * np;
    }
}

// ---------------- enc-B: (1024,8) + unroll-2 — the untested corner ---------
// No phase A (m pre-staged by prep), so the K-loop's unroll-2 frag regs fit
// the 64-reg budget spill-free AT 8 waves/SIMD (2 blocks/CU, 65.5 KB LDS).
// Max occupancy + pipelined loads + no spill, simultaneously.
__global__ __launch_bounds__(1024, 8) void encb_kernel(
    const float* __restrict__ xi,
    const ushort* __restrict__ Wt,
    const float* __restrict__ Bb1, const float* __restrict__ bb1,
    const float* __restrict__ Bw2, const float* __restrict__ Bb2,
    const float* __restrict__ bw2, const float* __restrict__ bb2,
    float* __restrict__ cw) {
    __shared__ ushort Ml[16 * MSTRIDE];   // ~33 KB
    __shared__ float red[3][2048];        // 24 KB
    __shared__ float hid[128][17];        // 8.5 KB

    const int tid = threadIdx.x;
    const int w = tid >> 6, lane = tid & 63;
    const int bb0 = blockIdx.x * 16;
    const int g = w & 3, q = w >> 2;
    const int r15 = lane & 15, kg = lane >> 4;

    // ---- stage m: 2 x gl_lds per wave (1 KB each, contiguous) ----
    {
        const ushort* mb = (const ushort*)(xi + (size_t)(bb0 + w) * 4096 + 512);
        gl_lds16(mb + lane * 8, &Ml[w * MSTRIDE]);
        gl_lds16(mb + 512 + lane * 8, &Ml[w * MSTRIDE + 512]);
    }
    asm volatile("s_waitcnt vmcnt(0)" ::: "memory");
    __syncthreads();

    // ---- phase B: wave (g,q), 8 staggered steps, unroll 2 ----
    {
        const ushort* wbase = Wt + (size_t)(q * 8) * 4096;
        const int aoff = (g * 32 + r15) * 32 + kg * 8;
        const int boff = r15 * MSTRIDE + q * 256 + kg * 8;
        const int rot = blockIdx.x & 7;

        f32x4 acc0 = {0.f, 0.f, 0.f, 0.f}, acc1 = acc0;
        #pragma unroll 2
        for (int s = 0; s < 8; ++s) {
            const int ss = (s + rot) & 7;
            const short8 a0 = *(const short8*)(wbase + ss * 4096 + aoff);
            const short8 a1 = *(const short8*)(wbase + ss * 4096 + aoff + 512);
            const short8 b = *(const short8*)&Ml[boff + ss * 32];
            acc0 = __builtin_amdgcn_mfma_f32_16x16x32_bf16(a0, b, acc0, 0, 0, 0);
            acc1 = __builtin_amdgcn_mfma_f32_16x16x32_bf16(a1, b, acc1, 0, 0, 0);
        }
        if (q > 0) {
            *(f32x4*)&red[q - 1][(g * 64 + lane) * 8] = acc0;
            *(f32x4*)&red[q - 1][(g * 64 + lane) * 8 + 4] = acc1;
        }
        __syncthreads();
        if (q == 0) {
            #pragma unroll
            for (int p = 0; p < 3; ++p) {
                acc0 += *(const f32x4*)&red[p][(g * 64 + lane) * 8];
                acc1 += *(const f32x4*)&red[p][(g * 64 + lane) * 8 + 4];
            }
            #pragma unroll
            for (int t = 0; t < 2; ++t) {
                #pragma unroll
                for (int r = 0; r < 4; ++r) {
                    const int h = g * 32 + t * 16 + kg * 4 + r;
                    const float bias = (h < 64) ? Bb1[h] : bb1[h - 64];
                    float v = (t ? acc1[r] : acc0[r]) + bias;
                    v = (h < 64) ? fmaxf(v, 0.f) : softplus_f(v);
                    hid[h][r15] = v;
                }
            }
        }
    }
    __syncthreads();

    // ---- layer 2 -> coef write (stats from prep at [26],[27]) ----
    if (tid < 128) {
        const int bl = tid >> 3, k = tid & 7;
        float dB = 0.f, db = 0.f;
        #pragma unroll 8
        for (int h = 0; h < 64; ++h) {
            dB = fmaf(hid[h][bl], Bw2[h * 8 + k], dB);
            db = fmaf(hid[64 + h][bl], bw2[h * 8 + k], db);
        }
        const float Bm = dB + Bb2[k];
        const float be = softplus_f(db + bb2[k]);
        float Bs = Bm;
        Bs += __shfl_xor(Bs, 1);
        Bs += __shfl_xor(Bs, 2);
        Bs += __shfl_xor(Bs, 4);
        float* cb = cw + (size_t)(bb0 + bl) * 32;
        cb[k] = 1.f - DTC * be * (Bm + Bs);
        cb[8 + k] = DTC * be * Bm;
        cb[16 + k] = Bm;
        if (k == 0) {
            cb[24] = Bs * (cb[27] + 1.f);   // sE2 from prep's E'
            cb[25] = cb[26];                // nu'
        }
    }
}

// ---------------- time loop — byte-identical to R12 ------------------------
__global__ __launch_bounds__(256) void time_kernel(
    const float* __restrict__ e, const float* __restrict__ ed,
    const float* __restrict__ cw, float* __restrict__ stress,
    float* __restrict__ xi_out) {
    __shared__ float els[4][512];
    __shared__ float pls[4][512];
    const int wv = threadIdx.x >> 6;
    const int wid = (blockIdx.x << 2) + wv;
    const int lane = threadIdx.x & 63;
    const int j = lane >> 3, k = lane & 7;

    const float* eb = e + (size_t)wid * NT;
    const float* edb = ed + (size_t)wid * NT;
    gl_lds16(eb + lane * 4, &els[wv][0]);
    gl_lds16(eb + 256 + lane * 4, &els[wv][256]);
    gl_lds16(edb + lane * 4, &pls[wv][0]);
    gl_lds16(edb + 256 + lane * 4, &pls[wv][256]);

    const float* cb = cw + (size_t)wid * 32;
    const float a = cb[k];
    const float c = cb[8 + k];
    const float Bm = cb[16 + k];
    const float sE2 = cb[24];
    const float nup = cb[25];
    asm volatile("s_waitcnt vmcnt(0)" ::: "memory");

    const float a2 = a * a, a4 = a2 * a2;
    float A = 1.f;
    if (j & 1) A *= a;
    if (j & 2) A *= a2;
    if (j & 4) A *= a4;
    float pw[8];
    {
        float run = c;
        #pragma unroll
        for (int i = 7; i >= 0; --i) {
            const bool on = (i < j);
            pw[i] = on ? run : 0.f;
            run = on ? run * a : run;
        }
    }

    float* xb = xi_out + (size_t)wid * (NT * 8);
    float* sb = stress + (size_t)wid * NT;
    const float* el = &els[wv][0];
    const float* pl = &pls[wv][0];

    float xs = 0.f;
    #pragma unroll
    for (int it = 0; it < 64; ++it) {
        const int t0 = it * 8;
        const float4 q0 = *(const float4*)(el + t0);
        const float4 q1 = *(const float4*)(el + t0 + 4);
        const float cuj = el[t0 + j];
        const float cpj = pl[t0 + j];
        float xi_j = A * xs;
        xi_j = fmaf(pw[0], q0.x, xi_j);
        xi_j = fmaf(pw[1], q0.y, xi_j);
        xi_j = fmaf(pw[2], q0.z, xi_j);
        xi_j = fmaf(pw[3], q0.w, xi_j);
        xi_j = fmaf(pw[4], q1.x, xi_j);
        xi_j = fmaf(pw[5], q1.y, xi_j);
        xi_j = fmaf(pw[6], q1.z, xi_j);
        xi_j = fmaf(pw[7], q1.w, xi_j);
        xb[t0 * 8 + lane] = xi_j;
        float r = Bm * xi_j;
        r = dpp_add(r, 0xB1);
        r = dpp_add(r, 0x4E);
        r = dpp_add(r, 0x141);
        if (k == 0)
            sb[t0 + j] = fmaf(cuj, sE2, fmaf(nup, cpj, -r));
        xs = fmaf(a, __shfl(xi_j, 56 + k), c * q1.w);
    }
}

extern "C" void kernel_launch(void* const* d_in, const int* in_sizes, int n_in,
                              void* d_out, int out_size, void* d_ws, size_t ws_size,
                              hipStream_t stream) {
    const float* e   = (const float*)d_in[0];
    const float* ed  = (const float*)d_in[1];
    const float* E   = (const float*)d_in[2];
    const float* nu  = (const float*)d_in[3];
    const float* Bw1 = (const float*)d_in[4];
    const float* Bb1 = (const float*)d_in[5];
    const float* Bw2 = (const float*)d_in[6];
    const float* Bb2 = (const float*)d_in[7];
    const float* bw1 = (const float*)d_in[8];
    const float* bb1 = (const float*)d_in[9];
    const float* bw2 = (const float*)d_in[10];
    const float* bb2 = (const float*)d_in[11];

    float* out = (float*)d_out;
    float* stress = out;                        // [B*T]
    float* xi = out + (size_t)NB * NT;          // [B*T*8]
    ushort* Wt = (ushort*)d_ws;                 // 256 KB tiled weights
    float* cw = (float*)((char*)d_ws + (1 << 20));   // coefs

    wtrans_kernel<<<128, 256, 0, stream>>>(Bw1, bw1, Wt);
    prep_kernel<<<2048, 256, 0, stream>>>(E, nu, xi, cw);
    encb_kernel<<<512, 1024, 0, stream>>>(xi, Wt, Bb1, bb1,
                                          Bw2, Bb2, bw2, bb2, cw);
    time_kernel<<<2048, 256, 0, stream>>>(e, ed, cw, stress, xi);
}

// Round 27
// 58.417 us; speedup vs baseline: 1.1851x; 1.1851x over previous
//
#include <hip/hip_runtime.h>
#include <hip/hip_bf16.h>

#define FEATN 501
#define KPAD 1024
#define MSTRIDE 1032   // Ml row stride (ushorts)
#define NB 8192
#define NT 512
#define DTC 0.01f

typedef __attribute__((ext_vector_type(8))) short short8;
typedef __attribute__((ext_vector_type(4))) float f32x4;

__device__ __forceinline__ float softplus_f(float x) {
    return fmaxf(x, 0.f) + log1pf(expf(-fabsf(x)));
}
__device__ __forceinline__ ushort f2bf(float x) {
    __hip_bfloat16 h = __float2bfloat16(x);   // RNE
    return *reinterpret_cast<ushort*>(&h);
}
__device__ __forceinline__ void gl_lds16(const void* g, void* l) {
    __builtin_amdgcn_global_load_lds(
        (const __attribute__((address_space(1))) void*)g,
        (__attribute__((address_space(3))) void*)l, 16, 0, 0);
}
__device__ __forceinline__ float dpp_add(float x, const int ctrl) {
    int s = __builtin_bit_cast(int, x);
    int y;
    switch (ctrl) {
    case 0xB1:  y = __builtin_amdgcn_update_dpp(0, s, 0xB1, 0xf, 0xf, true); break;
    case 0x4E:  y = __builtin_amdgcn_update_dpp(0, s, 0x4E, 0xf, 0xf, true); break;
    default:    y = __builtin_amdgcn_update_dpp(0, s, 0x141, 0xf, 0xf, true); break;
    }
    return x + __builtin_bit_cast(float, y);
}

// Wt2 tiled layout: idx(k,h) = ((s*128 + h)*4 + kg)*8 + kk
__global__ __launch_bounds__(256) void wtrans_kernel(
    const float* __restrict__ Bw1, const float* __restrict__ bw1,
    ushort* __restrict__ Wt) {
    const int h = blockIdx.x;
    const float* W = (h < 64) ? Bw1 : bw1;
    const int col = h & 63;
    #pragma unroll
    for (int it = 0; it < 4; ++it) {
        const int k = it * 256 + threadIdx.x;
        const int ksrc = (k < FEATN) ? k
                       : (k >= 512 && k < 512 + FEATN) ? k - 11 : -1;
        const float v = (ksrc >= 0) ? W[(size_t)ksrc * 64 + col] : 0.f;
        Wt[(size_t)(((k >> 5) * 128 + h) * 4 + ((k >> 3) & 3)) * 8 + (k & 7)] =
            f2bf(v);
    }
}

// ---------------- enc: R18 body at launch_bounds (1024,4) — best measured --
__global__ __launch_bounds__(1024, 4) void enc_kernel(
    const float* __restrict__ E, const float* __restrict__ nu,
    const ushort* __restrict__ Wt,
    const float* __restrict__ Bb1, const float* __restrict__ bb1,
    const float* __restrict__ Bw2, const float* __restrict__ Bb2,
    const float* __restrict__ bw2, const float* __restrict__ bb2,
    float* __restrict__ cw) {
    __shared__ ushort Ml[16 * MSTRIDE];   // ~33 KB
    __shared__ float red[3][2048];        // 24 KB
    __shared__ float hid[128][17];        // 8.5 KB
    __shared__ float nups[16], Eps[16];

    const int tid = threadIdx.x;
    const int w = tid >> 6, lane = tid & 63;
    const int bb0 = blockIdx.x * 16;
    const int g = w & 3, q = w >> 2;
    const int r15 = lane & 15, kg = lane >> 4;

    // ---- W half-preload: issue BEFORE phase A (overlaps its latency) ----
    const ushort* wbase = Wt + (size_t)(q * 8) * 4096;
    const int aoff = (g * 32 + r15) * 32 + kg * 8;
    const short8 pa0 = *(const short8*)(wbase + 0 * 4096 + aoff);
    const short8 pb0 = *(const short8*)(wbase + 0 * 4096 + aoff + 512);
    const short8 pa1 = *(const short8*)(wbase + 1 * 4096 + aoff);
    const short8 pb1 = *(const short8*)(wbase + 1 * 4096 + aoff + 512);
    const short8 pa2 = *(const short8*)(wbase + 2 * 4096 + aoff);
    const short8 pb2 = *(const short8*)(wbase + 2 * 4096 + aoff + 512);
    const short8 pa3 = *(const short8*)(wbase + 3 * 4096 + aoff);
    const short8 pb3 = *(const short8*)(wbase + 3 * 4096 + aoff + 512);

    // ---- phase A: one wave per batch, stride-64 dword loads ----
    {
        const size_t base = (size_t)(bb0 + w) * FEATN;
        float s1 = 0.f, s2 = 0.f;
        for (int i = lane; i < FEATN; i += 64) {
            const float Ev = E[base + i];
            const float nv = nu[base + i];
            const float inv = 1.0f / nv;
            s1 += inv;
            s2 = fmaf(Ev, inv * inv, s2);
            Ml[w * MSTRIDE + i] = f2bf(Ev);
            Ml[w * MSTRIDE + 512 + i] = f2bf(nv);
        }
        if (lane < 11) {                  // zero pads 501..511, 1013..1023
            Ml[w * MSTRIDE + FEATN + lane] = 0;
            Ml[w * MSTRIDE + 512 + FEATN + lane] = 0;
        }
        #pragma unroll
        for (int o = 32; o; o >>= 1) {
            s1 += __shfl_xor(s1, o);
            s2 += __shfl_xor(s2, o);
        }
        if (lane == 0) {
            const float np = (float)FEATN / s1;
            nups[w] = np;
            Eps[w] = (s2 / (float)FEATN) * np * np;
        }
    }
    __syncthreads();

    // ---- phase B: steps 0-3 from regs; 4-7 staggered L2 loads ----
    {
        const int boff = r15 * MSTRIDE + q * 256 + kg * 8;
        const int rot = blockIdx.x & 3;

        f32x4 acc0 = {0.f, 0.f, 0.f, 0.f}, acc1 = acc0;
        {
            const short8 b0 = *(const short8*)&Ml[boff + 0 * 32];
            acc0 = __builtin_amdgcn_mfma_f32_16x16x32_bf16(pa0, b0, acc0, 0, 0, 0);
            acc1 = __builtin_amdgcn_mfma_f32_16x16x32_bf16(pb0, b0, acc1, 0, 0, 0);
            const short8 b1 = *(const short8*)&Ml[boff + 1 * 32];
            acc0 = __builtin_amdgcn_mfma_f32_16x16x32_bf16(pa1, b1, acc0, 0, 0, 0);
            acc1 = __builtin_amdgcn_mfma_f32_16x16x32_bf16(pb1, b1, acc1, 0, 0, 0);
            const short8 b2 = *(const short8*)&Ml[boff + 2 * 32];
            acc0 = __builtin_amdgcn_mfma_f32_16x16x32_bf16(pa2, b2, acc0, 0, 0, 0);
            acc1 = __builtin_amdgcn_mfma_f32_16x16x32_bf16(pb2, b2, acc1, 0, 0, 0);
            const short8 b3 = *(const short8*)&Ml[boff + 3 * 32];
            acc0 = __builtin_amdgcn_mfma_f32_16x16x32_bf16(pa3, b3, acc0, 0, 0, 0);
            acc1 = __builtin_amdgcn_mfma_f32_16x16x32_bf16(pb3, b3, acc1, 0, 0, 0);
        }
        #pragma unroll
        for (int s = 0; s < 4; ++s) {
            const int ss = 4 + ((s + rot) & 3);
            const short8 a0 = *(const short8*)(wbase + ss * 4096 + aoff);
            const short8 a1 = *(const short8*)(wbase + ss * 4096 + aoff + 512);
            const short8 b = *(const short8*)&Ml[boff + ss * 32];
            acc0 = __builtin_amdgcn_mfma_f32_16x16x32_bf16(a0, b, acc0, 0, 0, 0);
            acc1 = __builtin_amdgcn_mfma_f32_16x16x32_bf16(a1, b, acc1, 0, 0, 0);
        }
        if (q > 0) {
            *(f32x4*)&red[q - 1][(g * 64 + lane) * 8] = acc0;
            *(f32x4*)&red[q - 1][(g * 64 + lane) * 8 + 4] = acc1;
        }
        __syncthreads();
        if (q == 0) {
            #pragma unroll
            for (int p = 0; p < 3; ++p) {
                acc0 += *(const f32x4*)&red[p][(g * 64 + lane) * 8];
                acc1 += *(const f32x4*)&red[p][(g * 64 + lane) * 8 + 4];
            }
            #pragma unroll
            for (int t = 0; t < 2; ++t) {
                #pragma unroll
                for (int r = 0; r < 4; ++r) {
                    const int h = g * 32 + t * 16 + kg * 4 + r;
                    const float bias = (h < 64) ? Bb1[h] : bb1[h - 64];
                    float v = (t ? acc1[r] : acc0[r]) + bias;
                    v = (h < 64) ? fmaxf(v, 0.f) : softplus_f(v);
                    hid[h][r15] = v;
                }
            }
        }
    }
    __syncthreads();

    // ---- layer 2 -> coef write (d_ws) ----
    if (tid < 128) {
        const int bl = tid >> 3, k = tid & 7;
        float dB = 0.f, db = 0.f;
        #pragma unroll 8
        for (int h = 0; h < 64; ++h) {
            dB = fmaf(hid[h][bl], Bw2[h * 8 + k], dB);
            db = fmaf(hid[64 + h][bl], bw2[h * 8 + k], db);
        }
        const float Bm = dB + Bb2[k];
        const float be = softplus_f(db + bb2[k]);
        float Bs = Bm;
        Bs += __shfl_xor(Bs, 1);
        Bs += __shfl_xor(Bs, 2);
        Bs += __shfl_xor(Bs, 4);
        float* cb = cw + (size_t)(bb0 + bl) * 32;
        cb[k] = 1.f - DTC * be * (Bm + Bs);
        cb[8 + k] = DTC * be * Bm;
        cb[16 + k] = Bm;
        if (k == 0) {
            cb[24] = Bs * (Eps[bl] + 1.f);
            cb[25] = nups[bl];
        }
    }
}

// ---------------- time loop — byte-identical to R12 ------------------------
__global__ __launch_bounds__(256) void time_kernel(
    const float* __restrict__ e, const float* __restrict__ ed,
    const float* __restrict__ cw, float* __restrict__ stress,
    float* __restrict__ xi_out) {
    __shared__ float els[4][512];
    __shared__ float pls[4][512];
    const int wv = threadIdx.x >> 6;
    const int wid = (blockIdx.x << 2) + wv;
    const int lane = threadIdx.x & 63;
    const int j = lane >> 3, k = lane & 7;

    const float* eb = e + (size_t)wid * NT;
    const float* edb = ed + (size_t)wid * NT;
    gl_lds16(eb + lane * 4, &els[wv][0]);
    gl_lds16(eb + 256 + lane * 4, &els[wv][256]);
    gl_lds16(edb + lane * 4, &pls[wv][0]);
    gl_lds16(edb + 256 + lane * 4, &pls[wv][256]);

    const float* cb = cw + (size_t)wid * 32;
    const float a = cb[k];
    const float c = cb[8 + k];
    const float Bm = cb[16 + k];
    const float sE2 = cb[24];
    const float nup = cb[25];
    asm volatile("s_waitcnt vmcnt(0)" ::: "memory");

    const float a2 = a * a, a4 = a2 * a2;
    float A = 1.f;
    if (j & 1) A *= a;
    if (j & 2) A *= a2;
    if (j & 4) A *= a4;
    float pw[8];
    {
        float run = c;
        #pragma unroll
        for (int i = 7; i >= 0; --i) {
            const bool on = (i < j);
            pw[i] = on ? run : 0.f;
            run = on ? run * a : run;
        }
    }

    float* xb = xi_out + (size_t)wid * (NT * 8);
    float* sb = stress + (size_t)wid * NT;
    const float* el = &els[wv][0];
    const float* pl = &pls[wv][0];

    float xs = 0.f;
    #pragma unroll
    for (int it = 0; it < 64; ++it) {
        const int t0 = it * 8;
        const float4 q0 = *(const float4*)(el + t0);
        const float4 q1 = *(const float4*)(el + t0 + 4);
        const float cuj = el[t0 + j];
        const float cpj = pl[t0 + j];
        float xi_j = A * xs;
        xi_j = fmaf(pw[0], q0.x, xi_j);
        xi_j = fmaf(pw[1], q0.y, xi_j);
        xi_j = fmaf(pw[2], q0.z, xi_j);
        xi_j = fmaf(pw[3], q0.w, xi_j);
        xi_j = fmaf(pw[4], q1.x, xi_j);
        xi_j = fmaf(pw[5], q1.y, xi_j);
        xi_j = fmaf(pw[6], q1.z, xi_j);
        xi_j = fmaf(pw[7], q1.w, xi_j);
        xb[t0 * 8 + lane] = xi_j;
        float r = Bm * xi_j;
        r = dpp_add(r, 0xB1);
        r = dpp_add(r, 0x4E);
        r = dpp_add(r, 0x141);
        if (k == 0)
            sb[t0 + j] = fmaf(cuj, sE2, fmaf(nup, cpj, -r));
        xs = fmaf(a, __shfl(xi_j, 56 + k), c * q1.w);
    }
}

extern "C" void kernel_launch(void* const* d_in, const int* in_sizes, int n_in,
                              void* d_out, int out_size, void* d_ws, size_t ws_size,
                              hipStream_t stream) {
    const float* e   = (const float*)d_in[0];
    const float* ed  = (const float*)d_in[1];
    const float* E   = (const float*)d_in[2];
    const float* nu  = (const float*)d_in[3];
    const float* Bw1 = (const float*)d_in[4];
    const float* Bb1 = (const float*)d_in[5];
    const float* Bw2 = (const float*)d_in[6];
    const float* Bb2 = (const float*)d_in[7];
    const float* bw1 = (const float*)d_in[8];
    const float* bb1 = (const float*)d_in[9];
    const float* bw2 = (const float*)d_in[10];
    const float* bb2 = (const float*)d_in[11];

    float* out = (float*)d_out;
    float* stress = out;                        // [B*T]
    float* xi = out + (size_t)NB * NT;          // [B*T*8]
    ushort* Wt = (ushort*)d_ws;                 // 256 KB tiled weights
    float* cw = (float*)((char*)d_ws + (1 << 20));   // coefs

    wtrans_kernel<<<128, 256, 0, stream>>>(Bw1, bw1, Wt);
    enc_kernel<<<512, 1024, 0, stream>>>(E, nu, Wt, Bb1, bb1,
                                         Bw2, Bb2, bw2, bb2, cw);
    time_kernel<<<2048, 256, 0, stream>>>(e, ed, cw, stress, xi);
}